// Round 1
// baseline (81.966 us; speedup 1.0000x reference)
//
#include <hip/hip_runtime.h>
#include <math.h>

// ---- 4-qubit statevector gate macros (all indices fold to constants) ----
// State: sr[16]/si[16], idx = a*8 + b*4 + c*2 + d  (wire w -> bit 3-w)

#define RY_GATE(bit, c_, s_) do {                                          \
    _Pragma("unroll")                                                      \
    for (int j = 0; j < 8; ++j) {                                          \
        const int lo = ((j >> (bit)) << ((bit) + 1)) | (j & ((1 << (bit)) - 1)); \
        const int hi = lo | (1 << (bit));                                  \
        float u0r = sr[lo], u0i = si[lo], u1r = sr[hi], u1i = si[hi];      \
        sr[lo] = (c_) * u0r - (s_) * u1r; si[lo] = (c_) * u0i - (s_) * u1i; \
        sr[hi] = (s_) * u0r + (c_) * u1r; si[hi] = (s_) * u0i + (c_) * u1i; \
    }                                                                      \
} while (0)

// Rx = [[c, -i s], [-i s, c]]
#define RX_GATE(bit, c_, s_) do {                                          \
    _Pragma("unroll")                                                      \
    for (int j = 0; j < 8; ++j) {                                          \
        const int lo = ((j >> (bit)) << ((bit) + 1)) | (j & ((1 << (bit)) - 1)); \
        const int hi = lo | (1 << (bit));                                  \
        float u0r = sr[lo], u0i = si[lo], u1r = sr[hi], u1i = si[hi];      \
        sr[lo] = (c_) * u0r + (s_) * u1i; si[lo] = (c_) * u0i - (s_) * u1r; \
        sr[hi] = (c_) * u1r + (s_) * u0i; si[hi] = (c_) * u1i - (s_) * u0r; \
    }                                                                      \
} while (0)

// Rz = diag(c - i s, c + i s)
#define RZ_GATE(bit, c_, s_) do {                                          \
    _Pragma("unroll")                                                      \
    for (int j = 0; j < 8; ++j) {                                          \
        const int lo = ((j >> (bit)) << ((bit) + 1)) | (j & ((1 << (bit)) - 1)); \
        const int hi = lo | (1 << (bit));                                  \
        float r0 = sr[lo], i0 = si[lo], r1 = sr[hi], i1 = si[hi];          \
        sr[lo] = (c_) * r0 + (s_) * i0; si[lo] = (c_) * i0 - (s_) * r0;    \
        sr[hi] = (c_) * r1 - (s_) * i1; si[hi] = (c_) * i1 + (s_) * r1;    \
    }                                                                      \
} while (0)

// CNOT: control bit cb set -> swap target-bit pair
#define CNOT_GATE(cb, tb) do {                                             \
    _Pragma("unroll")                                                      \
    for (int idx = 0; idx < 16; ++idx) {                                   \
        if (((idx >> (cb)) & 1) && !((idx >> (tb)) & 1)) {                 \
            const int o = idx | (1 << (tb));                               \
            float tr = sr[idx], ti = si[idx];                              \
            sr[idx] = sr[o]; si[idx] = si[o];                              \
            sr[o] = tr;      si[o] = ti;                                   \
        }                                                                  \
    }                                                                      \
} while (0)

__global__ __launch_bounds__(256) void quanv_fused_kernel(
    const float* __restrict__ x,     // (4096, 28, 28)
    const float* __restrict__ rp,    // (5,)
    const float* __restrict__ W,     // (10, 784)
    const float* __restrict__ bias,  // (10,)
    float* __restrict__ out)         // (4096, 10)
{
    const int img = blockIdx.x;
    const int tid = threadIdx.x;

    float acc[10];
#pragma unroll
    for (int c = 0; c < 10; ++c) acc[c] = 0.0f;

    if (tid < 196) {
        // ---- patch pixel loads: 2x2 patch (pr, pc), coalesced float2 per row
        const int pr = tid / 14;
        const int pc = tid - pr * 14;
        const float* px = x + (size_t)img * 784 + (2 * pr) * 28 + 2 * pc;
        const float2 r0 = *(const float2*)(px);
        const float2 r1 = *(const float2*)(px + 28);
        const float ang[4] = { r0.x, r0.y, r1.x, r1.y };

        // ---- initial product state |psi> = ⊗ Ry(ang_i)|0>  (real)
        float ca[4], sa[4];
#pragma unroll
        for (int i = 0; i < 4; ++i) __sincosf(0.5f * ang[i], &sa[i], &ca[i]);

        float sr[16], si[16];
#pragma unroll
        for (int a = 0; a < 2; ++a)
#pragma unroll
            for (int b = 0; b < 2; ++b)
#pragma unroll
                for (int c = 0; c < 2; ++c)
#pragma unroll
                    for (int d = 0; d < 2; ++d) {
                        const int idx = a * 8 + b * 4 + c * 2 + d;
                        sr[idx] = (a ? sa[0] : ca[0]) * (b ? sa[1] : ca[1]) *
                                  (c ? sa[2] : ca[2]) * (d ? sa[3] : ca[3]);
                        si[idx] = 0.0f;
                    }

        // ---- trainable gate angles (uniform, L1-cached)
        float gc[5], gs[5];
#pragma unroll
        for (int i = 0; i < 5; ++i) __sincosf(0.5f * rp[i], &gs[i], &gc[i]);

        // ---- fixed 8-op circuit (wire w -> bit 3-w)
        RY_GATE(3, gc[0], gs[0]);   // Ry(p0) wire 0
        RX_GATE(2, gc[1], gs[1]);   // Rx(p1) wire 1
        CNOT_GATE(3, 2);            // CNOT(0,1)
        RZ_GATE(1, gc[2], gs[2]);   // Rz(p2) wire 2
        RY_GATE(0, gc[3], gs[3]);   // Ry(p3) wire 3
        CNOT_GATE(1, 0);            // CNOT(2,3)
        RX_GATE(3, gc[4], gs[4]);   // Rx(p4) wire 0
        CNOT_GATE(2, 1);            // CNOT(1,2)

        // ---- PauliZ expectations per wire
        float ez0 = 0.f, ez1 = 0.f, ez2 = 0.f, ez3 = 0.f;
#pragma unroll
        for (int idx = 0; idx < 16; ++idx) {
            const float p = sr[idx] * sr[idx] + si[idx] * si[idx];
            ez0 += ((idx >> 3) & 1) ? -p : p;
            ez1 += ((idx >> 2) & 1) ? -p : p;
            ez2 += ((idx >> 1) & 1) ? -p : p;
            ez3 += ((idx >> 0) & 1) ? -p : p;
        }

        // ---- partial logits: feats columns for this patch are tid*4 .. tid*4+3
#pragma unroll
        for (int c = 0; c < 10; ++c) {
            const float4 wv = *(const float4*)(W + c * 784 + tid * 4);
            acc[c] = wv.x * ez0 + wv.y * ez1 + wv.z * ez2 + wv.w * ez3;
        }
    }

    // ---- block reduction: wave shuffle (width 64) then LDS combine
#pragma unroll
    for (int c = 0; c < 10; ++c) {
        float v = acc[c];
#pragma unroll
        for (int off = 32; off > 0; off >>= 1) v += __shfl_down(v, off, 64);
        acc[c] = v;
    }

    __shared__ float partial[4][10];
    __shared__ float logits_s[10];
    const int wave = tid >> 6;
    const int lane = tid & 63;
    if (lane == 0) {
#pragma unroll
        for (int c = 0; c < 10; ++c) partial[wave][c] = acc[c];
    }
    __syncthreads();

    if (tid < 10) {
        float l = bias[tid];
#pragma unroll
        for (int w = 0; w < 4; ++w) l += partial[w][tid];
        logits_s[tid] = l;
    }
    __syncthreads();

    if (tid < 10) {
        float m = -INFINITY;
#pragma unroll
        for (int c = 0; c < 10; ++c) m = fmaxf(m, logits_s[c]);
        float sum = 0.0f;
#pragma unroll
        for (int c = 0; c < 10; ++c) sum += __expf(logits_s[c] - m);
        out[(size_t)img * 10 + tid] = logits_s[tid] - m - __logf(sum);
    }
}

extern "C" void kernel_launch(void* const* d_in, const int* in_sizes, int n_in,
                              void* d_out, int out_size, void* d_ws, size_t ws_size,
                              hipStream_t stream) {
    const float* x    = (const float*)d_in[0];  // (4096,28,28)
    const float* rp   = (const float*)d_in[1];  // (5,)
    const float* W    = (const float*)d_in[2];  // (10,784)
    const float* bias = (const float*)d_in[3];  // (10,)
    float* out = (float*)d_out;                 // (4096,10)

    quanv_fused_kernel<<<4096, 256, 0, stream>>>(x, rp, W, bias, out);
}

// Round 2
// 78.085 us; speedup vs baseline: 1.0497x; 1.0497x over previous
//
#include <hip/hip_runtime.h>
#include <math.h>

// ---- 4-qubit statevector gate macros (all indices fold to constants) ----
// State: sr[16]/si[16], idx = a*8 + b*4 + c*2 + d  (wire w -> bit 3-w)

#define RY_GATE(bit, c_, s_) do {                                          \
    _Pragma("unroll")                                                      \
    for (int j = 0; j < 8; ++j) {                                          \
        const int lo = ((j >> (bit)) << ((bit) + 1)) | (j & ((1 << (bit)) - 1)); \
        const int hi = lo | (1 << (bit));                                  \
        float u0r = sr[lo], u0i = si[lo], u1r = sr[hi], u1i = si[hi];      \
        sr[lo] = (c_) * u0r - (s_) * u1r; si[lo] = (c_) * u0i - (s_) * u1i; \
        sr[hi] = (s_) * u0r + (c_) * u1r; si[hi] = (s_) * u0i + (c_) * u1i; \
    }                                                                      \
} while (0)

// Rx = [[c, -i s], [-i s, c]]
#define RX_GATE(bit, c_, s_) do {                                          \
    _Pragma("unroll")                                                      \
    for (int j = 0; j < 8; ++j) {                                          \
        const int lo = ((j >> (bit)) << ((bit) + 1)) | (j & ((1 << (bit)) - 1)); \
        const int hi = lo | (1 << (bit));                                  \
        float u0r = sr[lo], u0i = si[lo], u1r = sr[hi], u1i = si[hi];      \
        sr[lo] = (c_) * u0r + (s_) * u1i; si[lo] = (c_) * u0i - (s_) * u1r; \
        sr[hi] = (c_) * u1r + (s_) * u0i; si[hi] = (c_) * u1i - (s_) * u0r; \
    }                                                                      \
} while (0)

// Rz = diag(c - i s, c + i s)
#define RZ_GATE(bit, c_, s_) do {                                          \
    _Pragma("unroll")                                                      \
    for (int j = 0; j < 8; ++j) {                                          \
        const int lo = ((j >> (bit)) << ((bit) + 1)) | (j & ((1 << (bit)) - 1)); \
        const int hi = lo | (1 << (bit));                                  \
        float r0 = sr[lo], i0 = si[lo], r1 = sr[hi], i1 = si[hi];          \
        sr[lo] = (c_) * r0 + (s_) * i0; si[lo] = (c_) * i0 - (s_) * r0;    \
        sr[hi] = (c_) * r1 - (s_) * i1; si[hi] = (c_) * i1 + (s_) * r1;    \
    }                                                                      \
} while (0)

// CNOT: control bit cb set -> swap target-bit pair (pure register renaming)
#define CNOT_GATE(cb, tb) do {                                             \
    _Pragma("unroll")                                                      \
    for (int idx = 0; idx < 16; ++idx) {                                   \
        if (((idx >> (cb)) & 1) && !((idx >> (tb)) & 1)) {                 \
            const int o = idx | (1 << (tb));                               \
            float tr = sr[idx], ti = si[idx];                              \
            sr[idx] = sr[o]; si[idx] = si[o];                              \
            sr[o] = tr;      si[o] = ti;                                   \
        }                                                                  \
    }                                                                      \
} while (0)

__device__ __forceinline__ void sim_patch(const float ang[4],
                                          const float gc[5], const float gs[5],
                                          float ez[4])
{
    float ca[4], sa[4];
#pragma unroll
    for (int i = 0; i < 4; ++i) __sincosf(0.5f * ang[i], &sa[i], &ca[i]);

    // initial product state (real): sr[idx] = prod of c/s per wire, si = 0
    float ab[4] = { ca[0] * ca[1], ca[0] * sa[1], sa[0] * ca[1], sa[0] * sa[1] };
    float cd[4] = { ca[2] * ca[3], ca[2] * sa[3], sa[2] * ca[3], sa[2] * sa[3] };
    float sr[16], si[16];
#pragma unroll
    for (int h = 0; h < 4; ++h)
#pragma unroll
        for (int l = 0; l < 4; ++l)
            sr[h * 4 + l] = ab[h] * cd[l];

    // gate 1: Ry(rp0) on wire0 (bit3) -- real state stays real
#pragma unroll
    for (int j = 0; j < 8; ++j) {
        const int lo = j, hi = j | 8;
        float t0 = sr[lo], t1 = sr[hi];
        sr[lo] = gc[0] * t0 - gs[0] * t1;
        sr[hi] = gs[0] * t0 + gc[0] * t1;
    }
    // gate 2: Rx(rp1) on wire1 (bit2) -- real input -> complex output
#pragma unroll
    for (int j = 0; j < 8; ++j) {
        const int lo = ((j >> 2) << 3) | (j & 3);
        const int hi = lo | 4;
        float t0 = sr[lo], t1 = sr[hi];
        sr[lo] = gc[1] * t0;  si[lo] = -gs[1] * t1;
        sr[hi] = gc[1] * t1;  si[hi] = -gs[1] * t0;
    }
    CNOT_GATE(3, 2);            // CNOT(0,1)
    RZ_GATE(1, gc[2], gs[2]);   // Rz(rp2) wire 2
    RY_GATE(0, gc[3], gs[3]);   // Ry(rp3) wire 3
    CNOT_GATE(1, 0);            // CNOT(2,3)
    RX_GATE(3, gc[4], gs[4]);   // Rx(rp4) wire 0
    CNOT_GATE(2, 1);            // CNOT(1,2)

    // probabilities and PauliZ expectations: ez_w = 1 - 2 * sum_{bit set} p
    float p[16];
#pragma unroll
    for (int i = 0; i < 16; ++i)
        p[i] = fmaf(sr[i], sr[i], si[i] * si[i]);

    float S0 = 0.f, S1 = 0.f, S2 = 0.f, S3 = 0.f;
#pragma unroll
    for (int i = 0; i < 16; ++i) {
        if (i & 8) S0 += p[i];
        if (i & 4) S1 += p[i];
        if (i & 2) S2 += p[i];
        if (i & 1) S3 += p[i];
    }
    ez[0] = fmaf(-2.f, S0, 1.f);
    ez[1] = fmaf(-2.f, S1, 1.f);
    ez[2] = fmaf(-2.f, S2, 1.f);
    ez[3] = fmaf(-2.f, S3, 1.f);
}

// one wave (64 lanes) per image; 256-thread block = 4 images; no LDS, no barriers
__global__ __launch_bounds__(256, 4) void quanv_fused_kernel(
    const float* __restrict__ x,     // (4096, 28, 28)
    const float* __restrict__ rp,    // (5,)
    const float* __restrict__ W,     // (10, 784)
    const float* __restrict__ bias,  // (10,)
    float* __restrict__ out)         // (4096, 10)
{
    const int tid  = threadIdx.x;
    const int lane = tid & 63;
    const int img  = (blockIdx.x << 2) + (tid >> 6);

    // trainable gate angles (uniform -> scalar loads + redundant sincos)
    float gc[5], gs[5];
#pragma unroll
    for (int i = 0; i < 5; ++i) __sincosf(0.5f * rp[i], &gs[i], &gc[i]);

    float acc[10];
#pragma unroll
    for (int c = 0; c < 10; ++c) acc[c] = 0.0f;

    const float* xb = x + (size_t)img * 784;

#pragma unroll 1
    for (int k = 0; k < 4; ++k) {
        const int pidx = lane + (k << 6);
        if (pidx < 196) {
            const int pr = pidx / 14;
            const int pc = pidx - pr * 14;
            const float* px = xb + pr * 56 + pc * 2;
            const float2 r0 = *(const float2*)(px);
            const float2 r1 = *(const float2*)(px + 28);
            const float ang[4] = { r0.x, r0.y, r1.x, r1.y };

            float ez[4];
            sim_patch(ang, gc, gs, ez);

#pragma unroll
            for (int c = 0; c < 10; ++c) {
                const float4 wv = *(const float4*)(W + c * 784 + pidx * 4);
                acc[c] = fmaf(wv.x, ez[0],
                         fmaf(wv.y, ez[1],
                         fmaf(wv.z, ez[2],
                         fmaf(wv.w, ez[3], acc[c]))));
            }
        }
    }

    // width-64 butterfly: every lane ends with the full per-image sums
#pragma unroll
    for (int c = 0; c < 10; ++c) {
        float v = acc[c];
#pragma unroll
        for (int off = 32; off > 0; off >>= 1) v += __shfl_xor(v, off, 64);
        acc[c] = v + bias[c];
    }

    // log_softmax, redundantly per lane (all in registers)
    float m = acc[0];
#pragma unroll
    for (int c = 1; c < 10; ++c) m = fmaxf(m, acc[c]);
    float s = 0.0f;
#pragma unroll
    for (int c = 0; c < 10; ++c) s += __expf(acc[c] - m);
    const float lse = m + __logf(s);

    // lane c < 10 writes logit c (select chain, no dynamic register indexing)
    float myv = acc[0];
#pragma unroll
    for (int c = 1; c < 10; ++c) myv = (lane == c) ? acc[c] : myv;
    if (lane < 10) out[(size_t)img * 10 + lane] = myv - lse;
}

extern "C" void kernel_launch(void* const* d_in, const int* in_sizes, int n_in,
                              void* d_out, int out_size, void* d_ws, size_t ws_size,
                              hipStream_t stream) {
    const float* x    = (const float*)d_in[0];  // (4096,28,28)
    const float* rp   = (const float*)d_in[1];  // (5,)
    const float* W    = (const float*)d_in[2];  // (10,784)
    const float* bias = (const float*)d_in[3];  // (10,)
    float* out = (float*)d_out;                 // (4096,10)

    quanv_fused_kernel<<<1024, 256, 0, stream>>>(x, rp, W, bias, out);
}

// Round 3
// 71.290 us; speedup vs baseline: 1.1498x; 1.0953x over previous
//
#include <hip/hip_runtime.h>
#include <math.h>

// Closed-form quanvolution (derived via Heisenberg picture; verified against
// the statevector kernel that scored absmax 0.0 in R0-R2):
//   ez0 = cos(p4) * cos(x0 + p0)
//   ez1 = cos(p1) * cos(x0 + p0) * cos(x1)
//   ez2 = ez1 * cos(x2)
//   ez3 = cos(x2) * cos(x3 + p3)
// (p2 = Rz angle drops out of all Z expectations.)
// One wave per image; butterfly reduction; no LDS, no barriers.

__global__ __launch_bounds__(256, 4) void quanv_fused_kernel(
    const float* __restrict__ x,     // (4096, 28, 28)
    const float* __restrict__ rp,    // (5,)
    const float* __restrict__ W,     // (10, 784)
    const float* __restrict__ bias,  // (10,)
    float* __restrict__ out)         // (4096, 10)
{
    const int tid  = threadIdx.x;
    const int lane = tid & 63;
    const int img  = (blockIdx.x << 2) + (tid >> 6);

    // uniform trainable params (L1-cached scalar-ish loads)
    const float p0  = rp[0];
    const float cp1 = __cosf(rp[1]);
    const float p3  = rp[3];
    const float cp4 = __cosf(rp[4]);

    float acc[10];
#pragma unroll
    for (int c = 0; c < 10; ++c) acc[c] = 0.0f;

    const float* xb = x + (size_t)img * 784;

#pragma unroll
    for (int k = 0; k < 4; ++k) {
        const int pidx = lane + (k << 6);
        if (pidx < 196) {
            const int pr = pidx / 14;
            const int pc = pidx - pr * 14;
            const float* px = xb + pr * 56 + pc * 2;
            const float2 r0 = *(const float2*)(px);
            const float2 r1 = *(const float2*)(px + 28);

            const float z0 = __cosf(r0.x + p0);
            const float z1 = __cosf(r0.y);
            const float z2 = __cosf(r1.x);
            const float z3 = __cosf(r1.y + p3);

            const float ez0 = cp4 * z0;
            const float ez1 = cp1 * z0 * z1;
            const float ez2 = ez1 * z2;
            const float ez3 = z2 * z3;

#pragma unroll
            for (int c = 0; c < 10; ++c) {
                const float4 wv = *(const float4*)(W + c * 784 + pidx * 4);
                acc[c] = fmaf(wv.x, ez0,
                         fmaf(wv.y, ez1,
                         fmaf(wv.z, ez2,
                         fmaf(wv.w, ez3, acc[c]))));
            }
        }
    }

    // width-64 butterfly: every lane ends with the full per-image sums
#pragma unroll
    for (int c = 0; c < 10; ++c) {
        float v = acc[c];
#pragma unroll
        for (int off = 32; off > 0; off >>= 1) v += __shfl_xor(v, off, 64);
        acc[c] = v + bias[c];
    }

    // log_softmax, redundantly per lane (all in registers)
    float m = acc[0];
#pragma unroll
    for (int c = 1; c < 10; ++c) m = fmaxf(m, acc[c]);
    float s = 0.0f;
#pragma unroll
    for (int c = 0; c < 10; ++c) s += __expf(acc[c] - m);
    const float lse = m + __logf(s);

    // lane c < 10 writes logit c (select chain, no dynamic register indexing)
    float myv = acc[0];
#pragma unroll
    for (int c = 1; c < 10; ++c) myv = (lane == c) ? acc[c] : myv;
    if (lane < 10) out[(size_t)img * 10 + lane] = myv - lse;
}

extern "C" void kernel_launch(void* const* d_in, const int* in_sizes, int n_in,
                              void* d_out, int out_size, void* d_ws, size_t ws_size,
                              hipStream_t stream) {
    const float* x    = (const float*)d_in[0];  // (4096,28,28)
    const float* rp   = (const float*)d_in[1];  // (5,)
    const float* W    = (const float*)d_in[2];  // (10,784)
    const float* bias = (const float*)d_in[3];  // (10,)
    float* out = (float*)d_out;                 // (4096,10)

    quanv_fused_kernel<<<1024, 256, 0, stream>>>(x, rp, W, bias, out);
}